// Round 11
// baseline (133.256 us; speedup 1.0000x reference)
//
#include <hip/hip_runtime.h>
#include <hip/hip_bf16.h>

#define Bn 4
#define Sn 4096
#define Dn 64

typedef short          s16x8 __attribute__((ext_vector_type(8)));
typedef unsigned short u16x8 __attribute__((ext_vector_type(8)));
typedef float          f32x4 __attribute__((ext_vector_type(4)));

typedef __attribute__((address_space(1))) const void gas_void;
typedef __attribute__((address_space(3))) void       las_void;

__device__ __forceinline__ unsigned short f2bf(float f) {
    unsigned u = __float_as_uint(f);
    u = u + 0x7fffu + ((u >> 16) & 1u);   // RNE
    return (unsigned short)(u >> 16);
}
__device__ __forceinline__ float bf2f(unsigned short h) {
    return __uint_as_float(((unsigned)h) << 16);
}
__device__ __forceinline__ unsigned long long pack4(float4 x) {
    return (unsigned long long)f2bf(x.x)
         | ((unsigned long long)f2bf(x.y) << 16)
         | ((unsigned long long)f2bf(x.z) << 32)
         | ((unsigned long long)f2bf(x.w) << 48);
}
__device__ __forceinline__ void gld16(const void* g, void* l) {
    __builtin_amdgcn_global_load_lds((gas_void*)g, (las_void*)l, 16, 0, 0);
}

// ---------------------------------------------------------------------------
// Kernel 1 (init): 73 blocks x 256 threads.
//   blocks 0..7 : pack pad_mask into padbits (32 words of 64 cols each).
//   block 8     : zero meanVsum (256 floats).
//   blocks 9..72: zero Oacc + Lsum (4 MB + 64 KB, contiguous) [replaces memset]
// ---------------------------------------------------------------------------
__global__ void LPSAN_init_kernel(const unsigned char* pm, unsigned long long* padbits,
                                  float* meanVsum, float* Oacc) {
    const int k = blockIdx.x, t = threadIdx.x;
    if (k == 8) { meanVsum[t] = 0.f; return; }
    if (k >= 9) {                           // zero Oacc+Lsum: 266240 float4 total
        float4* dst = (float4*)Oacc;
        const float4 z = float4{0.f, 0.f, 0.f, 0.f};
        for (int i = (k - 9) * 256 + t; i < 266240; i += 64 * 256) dst[i] = z;
        return;
    }

    __shared__ unsigned nzs;
    if (t == 0) nzs = 0u;
    __syncthreads();
    { // detection: bytes [k*2048, (k+1)*2048) -- inside first 16KB, safe always
        const uint2* p2 = (const uint2*)(pm + k * 2048);
        uint2 x = p2[t];
        unsigned acc = (x.x & 0xFFFFFF00u) | (x.y & 0xFFFFFF00u);
        if (acc) atomicOr(&nzs, 1u);
    }
    __syncthreads();
    if (t >= 32) return;
    const int wi = k * 32 + t;              // padbits word index
    unsigned long long bits = 0ull;
    if (nzs) {                              // uint8 storage: 64 bytes
        const uint4* p4 = (const uint4*)(pm + wi * 64);
        #pragma unroll
        for (int q = 0; q < 4; ++q) {
            uint4 x = p4[q];
            unsigned w[4] = { x.x, x.y, x.z, x.w };
            #pragma unroll
            for (int wj = 0; wj < 4; ++wj)
                #pragma unroll
                for (int bb = 0; bb < 4; ++bb)
                    bits |= (unsigned long long)(((w[wj] >> (8 * bb)) & 0xFFu) != 0u)
                            << (q * 16 + wj * 4 + bb);
        }
    } else {                                // int32 storage: 64 ints
        const uint4* p4 = (const uint4*)pm + wi * 16;
        #pragma unroll
        for (int q = 0; q < 16; ++q) {
            uint4 x = p4[q];
            bits |= (unsigned long long)(x.x != 0u) << (q * 4);
            bits |= (unsigned long long)(x.y != 0u) << (q * 4 + 1);
            bits |= (unsigned long long)(x.z != 0u) << (q * 4 + 2);
            bits |= (unsigned long long)(x.w != 0u) << (q * 4 + 3);
        }
    }
    padbits[wi] = bits;
}

// ---------------------------------------------------------------------------
// Kernel 2: MFMA QKV projection.  32 rows/block, 512 blocks (2 blocks/CU for
// latency hiding -- the old 256x64 config ran 1 block/CU).  4 waves: wave w
// owns output-column tile w (16 cols) x 32 rows (2 row-tiles).  E and W
// staged bf16 + XOR swizzle; 4 MFMA per matrix per wave.  Epilogue through
// LDS for coalesced 16B stores.  meanVsum accumulated via atomics.
// ---------------------------------------------------------------------------
__global__ __launch_bounds__(256) void LPSAN_proj_kernel(
    const float* __restrict__ E, const float* __restrict__ PK, const float* __restrict__ PV,
    const float* __restrict__ Wq, const float* __restrict__ bq,
    const float* __restrict__ Wk, const float* __restrict__ bk,
    const float* __restrict__ Wv, const float* __restrict__ bv,
    unsigned short* __restrict__ Qb, unsigned short* __restrict__ Kb,
    unsigned short* __restrict__ Vt, float* __restrict__ meanVsum)
{
    __shared__ unsigned short Ebf[2048];        // [32][64] bf16, swizzled (4KB)
    __shared__ unsigned short Wbf[3][4096];     // swizzled (24KB)
    __shared__ unsigned short Tbuf[2560];       // Q/K: [32][72]; V: [64][40] (5KB)

    const int t = threadIdx.x;                  // 256 threads
    const int r0 = blockIdx.x * 32;
    const int b  = r0 >> 12;
    const int s0 = r0 & (Sn - 1);
    const int w = t >> 6, lane = t & 63;
    const int fq = lane >> 4, fr = lane & 15;

    { // stage E (32x64) + W (3x64x64): fp32 -> bf16, swizzled 8B writes
        const float4* Eg = (const float4*)(E + (size_t)r0 * 64);
        #pragma unroll
        for (int v = 0; v < 2; ++v) {
            int f = t + v * 256;
            float4 x = Eg[f];
            int row = f >> 4, c4 = f & 15;
            *(unsigned long long*)((char*)Ebf + row * 128 + ((c4 * 8) ^ ((row & 7) << 4))) = pack4(x);
        }
        #pragma unroll
        for (int m = 0; m < 3; ++m) {
            const float4* Wg = (const float4*)(m == 0 ? Wq : m == 1 ? Wk : Wv);
            #pragma unroll
            for (int v = 0; v < 4; ++v) {
                int f = t + v * 256;
                float4 x = Wg[f];
                int row = f >> 4, c4 = f & 15;
                *(unsigned long long*)((char*)Wbf[m] + row * 128 + ((c4 * 8) ^ ((row & 7) << 4))) = pack4(x);
            }
        }
    }
    __syncthreads();

    // A-frags: E[row = rt*16+fr][k = ks*32 + fq*8+i], rt = 0,1
    const char* Ec = (const char*)Ebf;
    const int  swz = (fr & 7) << 4;
    s16x8 ea[2][2];
    #pragma unroll
    for (int rt = 0; rt < 2; ++rt) {
        const int arow = rt * 16 + fr;
        ea[rt][0] = *(const s16x8*)(Ec + arow * 128 + ((fq * 16) ^ swz));
        ea[rt][1] = *(const s16x8*)(Ec + arow * 128 + ((64 + fq * 16) ^ swz));
    }
    const int jj = w * 16 + fr;                 // this lane's output column

    for (int m = 0; m < 3; ++m) {
        const char*  Wc   = (const char*)Wbf[m];
        const float* bias = (m == 0) ? bq : (m == 1) ? bk : bv;
        const float  bb   = bias[jj];

        // B-frag: W[j=jj][k=fq*8+i]
        s16x8 b0 = *(const s16x8*)(Wc + jj * 128 + ((fq * 16) ^ swz));
        s16x8 b1 = *(const s16x8*)(Wc + jj * 128 + ((64 + fq * 16) ^ swz));

        f32x4 acc[2];
        #pragma unroll
        for (int rt = 0; rt < 2; ++rt) {
            f32x4 z = f32x4{0.f, 0.f, 0.f, 0.f};
            z = __builtin_amdgcn_mfma_f32_16x16x32_bf16(ea[rt][0], b0, z, 0, 0, 0);
            z = __builtin_amdgcn_mfma_f32_16x16x32_bf16(ea[rt][1], b1, z, 0, 0, 0);
            acc[rt] = z;
        }

        if (m < 2) {                            // Q / K: Tbuf as [s(32)][72]
            #pragma unroll
            for (int rt = 0; rt < 2; ++rt)
                #pragma unroll
                for (int r = 0; r < 4; ++r) {
                    const int row = rt * 16 + fq * 4 + r;
                    float v = acc[rt][r] + bb;
                    v *= (m == 0) ? 0.125f : PK[(size_t)(r0 + row) * 64 + jj];
                    Tbuf[row * 72 + jj] = f2bf(v);
                }
            __syncthreads();
            { // coalesced read-back + 16B global stores (32 rows x 64 cols)
                u16x8 o = *(const u16x8*)&Tbuf[(t >> 3) * 72 + (t & 7) * 8];
                unsigned short* dst = (m == 0 ? Qb : Kb)
                    + (size_t)(b * Sn + s0 + (t >> 3)) * 64 + (t & 7) * 8;
                *(u16x8*)dst = o;
            }
            __syncthreads();
        } else {                                // V: Tbuf as [d(64)][40], b64 writes
            #pragma unroll
            for (int rt = 0; rt < 2; ++rt) {
                unsigned long long pk = 0;
                #pragma unroll
                for (int r = 0; r < 4; ++r) {
                    const int row = rt * 16 + fq * 4 + r;
                    float mod = PV[(size_t)(r0 + row) * 64 + jj];
                    pk |= (unsigned long long)f2bf((acc[rt][r] + bb) * mod) << (16 * r);
                }
                *(unsigned long long*)&Tbuf[jj * 40 + rt * 16 + fq * 4] = pk;
            }
            __syncthreads();
            {
                const int d = t >> 2, seg = t & 3;
                u16x8 o = *(const u16x8*)&Tbuf[d * 40 + seg * 8];
                *(u16x8*)(Vt + (size_t)(b * 64 + d) * Sn + s0 + seg * 8) = o;
                float s = 0.f;
                #pragma unroll
                for (int i = 0; i < 8; ++i) s += bf2f(o[i]);
                s += __shfl_xor(s, 1);
                s += __shfl_xor(s, 2);
                if ((t & 3) == 0) atomicAdd(&meanVsum[b * 64 + d], s);
            }
        }
    }
}

// ---------------------------------------------------------------------------
// Kernel 3: flash attention, split-KV, LDS-staged.  128 q-rows per block x
// 4 waves: each wave owns TWO 16-row q-sub-tiles sharing the same staged
// K/V tile (staging, barriers, atomics per unit work HALVE vs 64-row
// blocks; barrier stays 4-wave).  KV tiles of 64 double-buffered via
// global_load_lds (linear dest + inverse-swizzled source).  Static-offset
// softmax p = exp(s-16); row-sum via all-ones-B MFMA; masked entries 0.
// Block = (b, qi, chunk of <=8 KV tiles); qi = 128-row tile (0..31), chunks
// per qi = (qi>>2)+1; grid (144, 4), longest chunks first; 48KB LDS ->
// 3 blocks/CU, all 576 co-resident.  qi<4 writes final output directly;
// else fp32 atomicAdd into Oacc/Lsum.
// ---------------------------------------------------------------------------
__global__ __launch_bounds__(256) void LPSAN_attn_kernel(
    const unsigned short* __restrict__ Qb, const unsigned short* __restrict__ Kb,
    const unsigned short* __restrict__ Vt, const unsigned long long* __restrict__ padbits,
    const float* __restrict__ meanVsum,
    float* __restrict__ Oacc, float* __restrict__ Lsum, float* __restrict__ out)
{
    __shared__ unsigned short Klds[2][4096];   // [buf][64 kv x 64 d] swizzled (16KB)
    __shared__ unsigned short Vlds[2][4096];   // [buf][64 d x 64 kv] swizzled (16KB)
    __shared__ unsigned short Plds[4][2048];   // per-wave P, 2 subs x 16x64 (16KB)

    // --- map reversed blockIdx.x -> (qi, c); longest chunks first ---
    int id = 143 - blockIdx.x, g = 0, base = 0;
    while (id >= base + 4 * (g + 1)) { base += 4 * (g + 1); ++g; }
    const int rel = id - base;
    const int qi = 4 * g + rel / (g + 1);
    const int c  = rel % (g + 1);

    const int b = blockIdx.y;
    const int q0 = qi * 128;
    const int t0 = c * 8;
    const int ntiles = 2 * qi + 2;
    const int tcnt = min(8, ntiles - t0);
    const int tid = threadIdx.x;
    const int w = tid >> 6, lane = tid & 63;
    const int fq = lane >> 4, fr = lane & 15;
    const int qw0 = q0 + w * 32;                // sub s rows: [qw0+s*16, qw0+s*16+16)

    const unsigned short* Kbase = Kb + b * (Sn * Dn);
    const unsigned short* Vbase = Vt + b * (Dn * Sn);

    s16x8 qf[2][2];
    #pragma unroll
    for (int sub = 0; sub < 2; ++sub) {
        const unsigned short* qp = Qb + (size_t)(b * Sn + qw0 + sub * 16 + fr) * 64;
        qf[sub][0] = *(const s16x8*)(qp + fq * 8);
        qf[sub][1] = *(const s16x8*)(qp + 32 + fq * 8);
    }

    s16x8 onesb;                               // all-ones bf16 B operand
    #pragma unroll
    for (int i = 0; i < 8; ++i) onesb[i] = (short)0x3F80;

    f32x4 Oa[2][4];
    f32x4 lacc[2];
    #pragma unroll
    for (int s = 0; s < 2; ++s) {
        lacc[s] = f32x4{0.f, 0.f, 0.f, 0.f};
        #pragma unroll
        for (int i = 0; i < 4; ++i) Oa[s][i] = f32x4{0.f, 0.f, 0.f, 0.f};
    }

    char* Pw = (char*)&Plds[w][0];

    auto STAGE = [&](int kv0, int bufi) {
        #pragma unroll
        for (int cc = 0; cc < 2; ++cc) {
            int pos = w * 2048 + cc * 1024 + lane * 16;
            int row = pos >> 7;
            int cl  = (pos & 127) ^ ((row & 7) << 4);
            gld16(Kbase + (kv0 + row) * 64 + (cl >> 1),
                  (char*)&Klds[bufi][0] + w * 2048 + cc * 1024);
            gld16(Vbase + row * Sn + kv0 + (cl >> 1),
                  (char*)&Vlds[bufi][0] + w * 2048 + cc * 1024);
        }
    };

    auto COMPUTE = [&](int t, int bufi) {
        const char* Kc = (const char*)&Klds[bufi][0];
        const char* Vc = (const char*)&Vlds[bufi][0];
        const int kv0 = t * 64;
        const bool causal = (t >= 2 * qi);     // exact col>q mask is universally safe
        const unsigned long long bits = padbits[b * 64 + t];

        // --- per sub: QK^T scores -> p = exp(s-16) -> P to LDS ---
        #pragma unroll
        for (int sub = 0; sub < 2; ++sub) {
            const int qws = qw0 + sub * 16;
            f32x4 sc[4];
            #pragma unroll
            for (int tl = 0; tl < 4; ++tl) {
                int row = tl * 16 + fr;
                int swz = (row & 7) << 4;
                s16x8 k0 = *(const s16x8*)(Kc + row * 128 + ((fq * 16) ^ swz));
                s16x8 k1 = *(const s16x8*)(Kc + row * 128 + ((64 + fq * 16) ^ swz));
                f32x4 z = f32x4{0.f, 0.f, 0.f, 0.f};
                z = __builtin_amdgcn_mfma_f32_16x16x32_bf16(qf[sub][0], k0, z, 0, 0, 0);
                z = __builtin_amdgcn_mfma_f32_16x16x32_bf16(qf[sub][1], k1, z, 0, 0, 0);
                sc[tl] = z;
            }
            #pragma unroll
            for (int tl = 0; tl < 4; ++tl) {
                const bool pad = (bits >> (tl * 16 + fr)) & 1ull;
                const int col = kv0 + tl * 16 + fr;
                #pragma unroll
                for (int r = 0; r < 4; ++r) {
                    float p = __expf(sc[tl][r] - 16.0f);
                    bool msk = pad || (causal && (col > (qws + fq * 4 + r)));
                    sc[tl][r] = msk ? 0.f : p;
                }
            }
            char* Ps = Pw + sub * 2048;
            #pragma unroll
            for (int tl = 0; tl < 4; ++tl) {
                #pragma unroll
                for (int r = 0; r < 4; ++r) {
                    int prow = fq * 4 + r;
                    int pcb = (tl * 16 + fr) * 2;
                    *(unsigned short*)(Ps + prow * 128 + (pcb ^ ((prow & 7) << 4))) = f2bf(sc[tl][r]);
                }
            }
        }

        // --- V fragments hoisted once, shared by both subs ---
        s16x8 v0[4], v1[4];
        #pragma unroll
        for (int dt = 0; dt < 4; ++dt) {
            int row = dt * 16 + fr;
            int swz = (row & 7) << 4;
            v0[dt] = *(const s16x8*)(Vc + row * 128 + ((fq * 16) ^ swz));
            v1[dt] = *(const s16x8*)(Vc + row * 128 + ((64 + fq * 16) ^ swz));
        }
        asm volatile("s_waitcnt lgkmcnt(0)" ::: "memory");
        __builtin_amdgcn_sched_barrier(0);

        // --- per sub: PV + row-sum via ones-MFMA ---
        #pragma unroll
        for (int sub = 0; sub < 2; ++sub) {
            const char* Ps = Pw + sub * 2048;
            s16x8 pa0 = *(const s16x8*)(Ps + fr * 128 + ((fq * 16) ^ ((fr & 7) << 4)));
            s16x8 pa1 = *(const s16x8*)(Ps + fr * 128 + ((64 + fq * 16) ^ ((fr & 7) << 4)));
            lacc[sub] = __builtin_amdgcn_mfma_f32_16x16x32_bf16(pa0, onesb, lacc[sub], 0, 0, 0);
            lacc[sub] = __builtin_amdgcn_mfma_f32_16x16x32_bf16(pa1, onesb, lacc[sub], 0, 0, 0);
            #pragma unroll
            for (int dt = 0; dt < 4; ++dt) {
                Oa[sub][dt] = __builtin_amdgcn_mfma_f32_16x16x32_bf16(pa0, v0[dt], Oa[sub][dt], 0, 0, 0);
                Oa[sub][dt] = __builtin_amdgcn_mfma_f32_16x16x32_bf16(pa1, v1[dt], Oa[sub][dt], 0, 0, 0);
            }
        }
    };

    // --- pipeline: STAGE(next) overlaps COMPUTE(cur); one barrier/tile ---
    STAGE(t0 * 64, 0);
    asm volatile("s_waitcnt vmcnt(0)" ::: "memory");
    __builtin_amdgcn_s_barrier();
    int cur = 0;
    for (int i = 0; i < tcnt - 1; ++i) {
        STAGE((t0 + i + 1) * 64, cur ^ 1);
        COMPUTE(t0 + i, cur);
        asm volatile("s_waitcnt vmcnt(0)" ::: "memory");
        __builtin_amdgcn_s_barrier();
        cur ^= 1;
    }
    COMPUTE(t0 + tcnt - 1, cur);

    if (ntiles <= 8) {
        // --- single chunk (qi<4): final output directly (fp32) ---
        #pragma unroll
        for (int sub = 0; sub < 2; ++sub)
            #pragma unroll
            for (int r = 0; r < 4; ++r) {
                int qrow = qw0 + sub * 16 + fq * 4 + r;
                float l = lacc[sub][r];
                bool dead = !(l > 0.f);
                float inv = dead ? 0.f : 1.0f / l;
                #pragma unroll
                for (int dt = 0; dt < 4; ++dt) {
                    int d = dt * 16 + fr;
                    float val = dead ? meanVsum[b * 64 + d] * (1.0f / (float)Sn)
                                     : Oa[sub][dt][r] * inv;
                    out[((size_t)(b * Sn + qrow)) * 64 + d] = val;
                }
            }
    } else {
        // --- accumulate unnormalized partial into fp32 Oacc/Lsum ---
        #pragma unroll
        for (int sub = 0; sub < 2; ++sub)
            #pragma unroll
            for (int r = 0; r < 4; ++r) {
                int qrow = qw0 + sub * 16 + fq * 4 + r;
                if (fr == 0) atomicAdd(&Lsum[b * Sn + qrow], lacc[sub][r]);
                #pragma unroll
                for (int dt = 0; dt < 4; ++dt)
                    atomicAdd(&Oacc[((size_t)(b * Sn + qrow)) * 64 + dt * 16 + fr], Oa[sub][dt][r]);
            }
    }
}

// ---------------------------------------------------------------------------
// Kernel 4 (normalize): rows >= 512 only (qi >= 4).  out = Oacc / Lsum.
// Dead row (Lsum == 0): reference softmax uniform over ALL S -> meanV.
// ---------------------------------------------------------------------------
__global__ void LPSAN_norm_kernel(
    const float* __restrict__ Oacc, const float* __restrict__ Lsum,
    const float* __restrict__ meanVsum, float* __restrict__ out)
{
    const int qt = 8 + blockIdx.x, b = blockIdx.y;
    const int t = threadIdx.x;
    const int row = t >> 2, q4 = t & 3;
    const int qrow = qt * 64 + row;

    const float l = Lsum[b * Sn + qrow];
    const bool dead = !(l > 0.f);
    const float inv = dead ? 0.f : 1.0f / l;

    const float* src = Oacc + ((size_t)(b * Sn + qrow)) * 64 + q4 * 16;
    float*       dst = out  + ((size_t)(b * Sn + qrow)) * 64 + q4 * 16;
    #pragma unroll
    for (int v = 0; v < 4; ++v) {
        float4 x = *(const float4*)(src + v * 4);
        float4 o;
        if (dead) {
            const float* mv = meanVsum + b * 64 + q4 * 16 + v * 4;
            o.x = mv[0] * (1.0f / (float)Sn);
            o.y = mv[1] * (1.0f / (float)Sn);
            o.z = mv[2] * (1.0f / (float)Sn);
            o.w = mv[3] * (1.0f / (float)Sn);
        } else {
            o.x = x.x * inv; o.y = x.y * inv; o.z = x.z * inv; o.w = x.w * inv;
        }
        *(float4*)(dst + v * 4) = o;
    }
}

// ---------------------------------------------------------------------------
extern "C" void kernel_launch(void* const* d_in, const int* in_sizes, int n_in,
                              void* d_out, int out_size, void* d_ws, size_t ws_size,
                              hipStream_t stream) {
    const float* E  = (const float*)d_in[0];
    const float* PK = (const float*)d_in[1];
    const float* PV = (const float*)d_in[2];
    const float* Wq = (const float*)d_in[3];
    const float* bq = (const float*)d_in[4];
    const float* Wk = (const float*)d_in[5];
    const float* bk = (const float*)d_in[6];
    const float* Wv = (const float*)d_in[7];
    const float* bv = (const float*)d_in[8];
    const unsigned char* pm = (const unsigned char*)d_in[9];

    char* ws = (char*)d_ws;
    const size_t SZ = (size_t)Bn * Sn * Dn * sizeof(unsigned short);   // 2 MB each
    const size_t OB = (size_t)Bn * Sn * Dn * sizeof(float);            // 4 MB
    const size_t LB = (size_t)Bn * Sn * sizeof(float);                 // 64 KB
    unsigned short* Qb = (unsigned short*)(ws);
    unsigned short* Kb = (unsigned short*)(ws + SZ);
    unsigned short* Vt = (unsigned short*)(ws + 2 * SZ);
    float* Oacc = (float*)(ws + 3 * SZ);
    float* Lsum = (float*)(ws + 3 * SZ + OB);
    unsigned long long* padbits = (unsigned long long*)(ws + 3 * SZ + OB + LB);
    float* meanVsum = (float*)(ws + 3 * SZ + OB + LB + 4096);
    float* out = (float*)d_out;

    hipLaunchKernelGGL(LPSAN_init_kernel, dim3(73), dim3(256), 0, stream,
                       pm, padbits, meanVsum, Oacc);
    hipLaunchKernelGGL(LPSAN_proj_kernel, dim3(Bn * Sn / 32), dim3(256), 0, stream,
                       E, PK, PV, Wq, bq, Wk, bk, Wv, bv, Qb, Kb, Vt, meanVsum);
    hipLaunchKernelGGL(LPSAN_attn_kernel, dim3(144, Bn), dim3(256), 0, stream,
                       Qb, Kb, Vt, padbits, meanVsum, Oacc, Lsum, out);
    hipLaunchKernelGGL(LPSAN_norm_kernel, dim3(56, Bn), dim3(256), 0, stream,
                       Oacc, Lsum, meanVsum, out);
}